// Round 4
// baseline (475.345 us; speedup 1.0000x reference)
//
#include <hip/hip_runtime.h>
#include <cmath>

using u16 = unsigned short;
using u32 = unsigned int;
using bf16x8 = __attribute__((ext_vector_type(8))) __bf16;
using f32x4  = __attribute__((ext_vector_type(4))) float;

__device__ inline u16 f2bf(float f) {
  u32 u = __float_as_uint(f);
  u32 r = (u + 0x7fffu + ((u >> 16) & 1u)) >> 16;  // RNE
  return (u16)r;
}

// ---------------- LayerNorm: x[row][1024] f32 -> xn bf16 ----------------
__global__ __launch_bounds__(256) void ln_kernel(
    const float* __restrict__ x, const float* __restrict__ w,
    const float* __restrict__ b, u16* __restrict__ xn) {
  int row = blockIdx.x;
  const float4* xr = (const float4*)(x + (size_t)row * 1024);
  float4 v = xr[threadIdx.x];
  float s  = v.x + v.y + v.z + v.w;
  float ss = v.x * v.x + v.y * v.y + v.z * v.z + v.w * v.w;
  int lane = threadIdx.x & 63, wave = threadIdx.x >> 6;
#pragma unroll
  for (int o = 32; o >= 1; o >>= 1) {
    s  += __shfl_xor(s, o, 64);
    ss += __shfl_xor(ss, o, 64);
  }
  __shared__ float rs[4], rq[4];
  if (lane == 0) { rs[wave] = s; rq[wave] = ss; }
  __syncthreads();
  s  = rs[0] + rs[1] + rs[2] + rs[3];
  ss = rq[0] + rq[1] + rq[2] + rq[3];
  float mean = s * (1.0f / 1024.0f);
  float var  = ss * (1.0f / 1024.0f) - mean * mean;
  float rstd = rsqrtf(var + 1e-5f);
  int c = threadIdx.x * 4;
  ushort4 ov;
  ov.x = f2bf((v.x - mean) * rstd * w[c + 0] + b[c + 0]);
  ov.y = f2bf((v.y - mean) * rstd * w[c + 1] + b[c + 1]);
  ov.z = f2bf((v.z - mean) * rstd * w[c + 2] + b[c + 2]);
  ov.w = f2bf((v.w - mean) * rstd * w[c + 3] + b[c + 3]);
  ((ushort4*)(xn + (size_t)row * 1024))[threadIdx.x] = ov;
}

// ---------------- weight transpose f32 [R][C] -> bf16 [C][R] ----------------
__global__ __launch_bounds__(256) void transpose_w(
    const float* __restrict__ in, u16* __restrict__ out, int R, int C) {
  __shared__ float tile[32][33];
  int c0 = blockIdx.x * 32, r0 = blockIdx.y * 32;
  int tx = threadIdx.x, ty = threadIdx.y;  // block (32,8)
#pragma unroll
  for (int i = 0; i < 32; i += 8)
    tile[ty + i][tx] = in[(size_t)(r0 + ty + i) * C + c0 + tx];
  __syncthreads();
#pragma unroll
  for (int i = 0; i < 32; i += 8)
    out[(size_t)(c0 + ty + i) * R + r0 + tx] = f2bf(tile[tx][ty + i]);
}

// ---------------- bias concat: bq|bk|bv -> bqkv[3072] ----------------
__global__ void concat_bias(const float* __restrict__ bq, const float* __restrict__ bk,
                            const float* __restrict__ bv, float* __restrict__ o) {
  int i = blockIdx.x * 1024 + threadIdx.x;
  const float* src = (blockIdx.x == 0) ? bq : (blockIdx.x == 1) ? bk : bv;
  o[i] = src[threadIdx.x];
}

// ---------------- masked row softmax over scores fp32, writes P bf16 in-place --
__global__ __launch_bounds__(256) void softmax_kernel(float* __restrict__ scores) {
  int row = blockIdx.x;
  int s = row & 2047;
  float* srow = scores + (size_t)row * 2048;
  int tid = threadIdx.x;
  int lane = tid & 63, wave = tid >> 6;
  const float FINF = __builtin_inff();
  float x[8];
  float m = -FINF;
#pragma unroll
  for (int i = 0; i < 8; i++) {
    int t = s + tid + i * 256;
    float v = -FINF;
    if (t < 2048) {
      v = srow[t];
      v = fminf(fmaxf(v, -1.0e9f), 1.0e9f);  // CLAMP
    }
    x[i] = v;
    m = fmaxf(m, v);
  }
#pragma unroll
  for (int o = 32; o >= 1; o >>= 1) m = fmaxf(m, __shfl_xor(m, o, 64));
  __shared__ float rm[4], rsum[4];
  if (lane == 0) rm[wave] = m;
  __syncthreads();
  m = fmaxf(fmaxf(rm[0], rm[1]), fmaxf(rm[2], rm[3]));
  float sum = 0.f;
#pragma unroll
  for (int i = 0; i < 8; i++) {
    x[i] = __expf(x[i] - m);
    sum += x[i];
  }
#pragma unroll
  for (int o = 32; o >= 1; o >>= 1) sum += __shfl_xor(sum, o, 64);
  if (lane == 0) rsum[wave] = sum;
  __syncthreads();
  sum = rsum[0] + rsum[1] + rsum[2] + rsum[3];
  float inv = 1.0f / sum;
  u16* prow = (u16*)srow;
  for (int t = tid; t < s; t += 256) prow[t] = 0;
#pragma unroll
  for (int i = 0; i < 8; i++) {
    int t = s + tid + i * 256;
    if (t < 2048) prow[t] = f2bf(x[i] * inv);
  }
}

// ---------------- 256x256 8-phase bf16 GEMM, B^T layout (m201 schedule) ------
// C[M,N] = A[M,K] * Bt[N,K]^T. BK=64, 8 waves (2Mx4N), wave tile 128x64.
// Half-tiles in READ-ORDER; 1 half staged per phase; vmcnt(6) at P4/P8.
// R4 change: NO explicit lgkmcnt(0) — compiler emits counted per-operand
// waits, so MFMA block mm starts as soon as its frags land while later
// ds_reads drain under the MFMA clusters (ds-pipe ∥ MFMA-pipe overlap).
// Reads ordered B-first / A mm-major so first MFMA's operands are oldest.
// WAR safety: every read is consumed by an MFMA in its phase, so reads are
// drained before each wave's last MFMA issue, which precedes the exit BAR.
// MODE 0: plain. MODE 1: QK (skip tj<ti). MODE 2: PV (k0 = ti*256).
template <int OUTF32, int MODE>
__global__ __launch_bounds__(512, 2) void gemm256(
    const u16* __restrict__ A, const u16* __restrict__ B, void* __restrict__ Cv,
    const float* __restrict__ bias, int K, int lda, int ldb, int ldc,
    float scale, long long sA, long long sB, long long sC) {
  // XCD-aware bijective swizzle of (x,y) linear index
  int gx = gridDim.x;
  int wg = blockIdx.y * gx + blockIdx.x;
  {
    int nwg = gx * gridDim.y;
    if ((nwg & 7) == 0) {
      int q = nwg >> 3;
      wg = (wg & 7) * q + (wg >> 3);
    }
  }
  const int ti = wg / gx, tj = wg % gx, bz = blockIdx.z;
  if (MODE == 1 && tj < ti) return;  // fully-masked score tile

  const u16* Ab = A + (size_t)bz * (size_t)sA;
  const u16* Bb = B + (size_t)bz * (size_t)sB;

  __shared__ u16 As[2][256 * 64];  // 64 KiB
  __shared__ u16 Bs[2][256 * 64];  // 64 KiB

  const int tid = threadIdx.x;
  const int wave = tid >> 6, lane = tid & 63;
  const int wr = wave >> 2, wc = wave & 3;  // 2 x 4 wave grid
  const int fr = lane & 15;
  const int kb16 = (lane >> 4) * 16;        // byte offset of k-frag in 64B k-block
  const int swz = (fr & 7) << 4;
  const int cs0 = kb16 ^ swz;               // ks=0 swizzled col byte
  const int cs1 = (64 + kb16) ^ swz;        // ks=1
  const int aRowOff = (wr * 128 + fr) * 128;  // bytes
  const int bRowOff = (wc * 64 + fr) * 128;

  // Staging precompute: per (half h, l) -> global offset + LDS byte offset.
  size_t gAo[2][2], gBo[2][2];
  u32 ldsA[2][2], ldsB[2][2];
#pragma unroll
  for (int h = 0; h < 2; ++h) {
#pragma unroll
    for (int l = 0; l < 2; ++l) {
      int i = l * 512 + tid;
      int rih = i >> 3, ch8 = i & 7;
      // A: rows {0-63,128-191}+64h
      int rA = (rih & 63) + ((rih >> 6) << 7) + h * 64;
      int cbA = (ch8 << 4) ^ ((rA & 7) << 4);  // pre-swizzled source byte col
      gAo[h][l] = (size_t)rA * lda + (cbA >> 1);
      ldsA[h][l] = (u32)(rA * 8 + ch8) * 16;
      // B: rows {(r&63)<32}+32h
      int rB = (rih & 31) + ((rih >> 5) << 6) + h * 32;
      int cbB = (ch8 << 4) ^ ((rB & 7) << 4);
      gBo[h][l] = (size_t)rB * ldb + (cbB >> 1);
      ldsB[h][l] = (u32)(rB * 8 + ch8) * 16;
    }
  }
  const size_t aBase = (size_t)(ti * 256) * lda;
  const size_t bBase = (size_t)(tj * 256) * ldb;

  const int k0 = (MODE == 2) ? ti * 256 : 0;
  const int niter = (K - k0) / 128;  // 2 K-tiles per iteration

  f32x4 acc[8][4] = {};
  bf16x8 aF[4][2], bF[4][2];

#define GLL(gaddr, laddr)                                        \
  __builtin_amdgcn_global_load_lds(                              \
      (const __attribute__((address_space(1))) void*)(gaddr),    \
      (__attribute__((address_space(3))) void*)(laddr), 16, 0, 0)

#define STAGE_A(buf, h, t)                                                     \
  do {                                                                         \
    const size_t _kt = aBase + (size_t)(k0 + (t) * 64);                        \
    GLL(Ab + _kt + gAo[h][0], (char*)&As[buf][0] + ldsA[h][0]);                \
    GLL(Ab + _kt + gAo[h][1], (char*)&As[buf][0] + ldsA[h][1]);                \
  } while (0)
#define STAGE_B(buf, h, t)                                                     \
  do {                                                                         \
    const size_t _kt = bBase + (size_t)(k0 + (t) * 64);                        \
    GLL(Bb + _kt + gBo[h][0], (char*)&Bs[buf][0] + ldsB[h][0]);                \
    GLL(Bb + _kt + gBo[h][1], (char*)&Bs[buf][0] + ldsB[h][1]);                \
  } while (0)

#define DS_A(buf, qm)                                                \
  do {                                                               \
    const char* _pa = (const char*)&As[buf][0] + aRowOff + (qm)*8192;\
    _Pragma("unroll") for (int mm = 0; mm < 4; ++mm) {               \
      aF[mm][0] = *(const bf16x8*)(_pa + mm * 2048 + cs0);           \
      aF[mm][1] = *(const bf16x8*)(_pa + mm * 2048 + cs1);           \
    }                                                                \
  } while (0)
#define DS_B(buf, nh)                                                \
  do {                                                               \
    const char* _pb = (const char*)&Bs[buf][0] + bRowOff;            \
    _Pragma("unroll") for (int nn = 0; nn < 2; ++nn) {               \
      bF[(nh)*2 + nn][0] = *(const bf16x8*)(_pb + ((nh)*2 + nn) * 2048 + cs0); \
      bF[(nh)*2 + nn][1] = *(const bf16x8*)(_pb + ((nh)*2 + nn) * 2048 + cs1); \
    }                                                                \
  } while (0)

#define MMA(qm, nh)                                                          \
  do {                                                                       \
    _Pragma("unroll") for (int mm = 0; mm < 4; ++mm)                         \
    _Pragma("unroll") for (int nn = 0; nn < 2; ++nn) {                       \
      f32x4 _c = acc[(qm)*4 + mm][(nh)*2 + nn];                              \
      _c = __builtin_amdgcn_mfma_f32_16x16x32_bf16(aF[mm][0], bF[(nh)*2+nn][0], _c, 0, 0, 0); \
      _c = __builtin_amdgcn_mfma_f32_16x16x32_bf16(aF[mm][1], bF[(nh)*2+nn][1], _c, 0, 0, 0); \
      acc[(qm)*4 + mm][(nh)*2 + nn] = _c;                                    \
    }                                                                        \
  } while (0)

#define BAR __builtin_amdgcn_s_barrier()
#define VM6 asm volatile("s_waitcnt vmcnt(6)" ::: "memory")
#define VM0 asm volatile("s_waitcnt vmcnt(0)" ::: "memory")
#define PRIO1 __builtin_amdgcn_s_setprio(1)
#define PRIO0 __builtin_amdgcn_s_setprio(0)

  // Prologue: tile0 all 4 halves (read-order) + tile1 B-h0,B-h1,A-h0 = 14 ops.
  STAGE_B(0, 0, 0); STAGE_B(0, 1, 0); STAGE_A(0, 0, 0); STAGE_A(0, 1, 0);
  STAGE_B(1, 0, 1); STAGE_B(1, 1, 1); STAGE_A(1, 0, 1);
  VM6; BAR;  // tile0 fully landed; 3 half-tiles (tile1 B+A-h0) in flight

  for (int it = 0; it < niter; ++it) {
    const bool last = (it == niter - 1);
    const int t1g = 2 * it + 1, t2g = 2 * it + 2, t3g = 2 * it + 3;

    // ---- P1: stage A-h1(t1g)->buf1; read buf0 B-nh0 then A-qm0 (B oldest)
    STAGE_A(1, 1, t1g);
    DS_B(0, 0); DS_A(0, 0);
    BAR; PRIO1; MMA(0, 0); PRIO0; BAR;
    // ---- P2: stage B-h0(t2g)->buf0; read buf0 B-nh1
    if (!last) STAGE_B(0, 0, t2g);
    DS_B(0, 1);
    BAR; PRIO1; MMA(0, 1); PRIO0; BAR;
    // ---- P3: stage B-h1(t2g); read buf0 A-qm1
    if (!last) STAGE_B(0, 1, t2g);
    DS_A(0, 1);
    BAR; PRIO1; MMA(1, 0); PRIO0; BAR;
    // ---- P4: stage A-h0(t2g); K-tile wait (lands ALL of tile t1g)
    if (!last) STAGE_A(0, 0, t2g);
    BAR; PRIO1; MMA(1, 1); PRIO0;
    if (last) { VM0; } else { VM6; }
    BAR;
    // ---- P5: stage A-h1(t2g); read buf1 B-nh0 then A-qm0
    if (!last) STAGE_A(0, 1, t2g);
    DS_B(1, 0); DS_A(1, 0);
    BAR; PRIO1; MMA(0, 0); PRIO0; BAR;
    // ---- P6: stage B-h0(t3g)->buf1; read buf1 B-nh1
    if (!last) STAGE_B(1, 0, t3g);
    DS_B(1, 1);
    BAR; PRIO1; MMA(0, 1); PRIO0; BAR;
    // ---- P7: stage B-h1(t3g); read buf1 A-qm1
    if (!last) STAGE_B(1, 1, t3g);
    DS_A(1, 1);
    BAR; PRIO1; MMA(1, 0); PRIO0; BAR;
    // ---- P8: stage A-h0(t3g); K-tile wait (lands ALL of tile t2g)
    if (!last) STAGE_A(1, 0, t3g);
    BAR; PRIO1; MMA(1, 1); PRIO0;
    if (!last) VM6;
    BAR;
  }

  // Epilogue: C/D layout col=lane&15, row=(lane>>4)*4+j
  const int orow0 = ti * 256 + wr * 128 + ((lane >> 4) << 2);
  const int ocol0 = tj * 256 + wc * 64 + fr;
#pragma unroll
  for (int m = 0; m < 8; ++m) {
#pragma unroll
    for (int n = 0; n < 4; ++n) {
      const int col = ocol0 + n * 16;
      const float bv = bias ? bias[col] : 0.0f;
#pragma unroll
      for (int j = 0; j < 4; ++j) {
        const int row = orow0 + m * 16 + j;
        const float v = acc[m][n][j] * scale + bv;
        const size_t idx = (size_t)bz * (size_t)sC + (size_t)row * ldc + col;
        if (OUTF32) ((float*)Cv)[idx] = v;
        else        ((u16*)Cv)[idx]   = f2bf(v);
      }
    }
  }
#undef GLL
#undef STAGE_A
#undef STAGE_B
#undef DS_A
#undef DS_B
#undef MMA
#undef BAR
#undef VM6
#undef VM0
#undef PRIO1
#undef PRIO0
}

extern "C" void kernel_launch(void* const* d_in, const int* in_sizes, int n_in,
                              void* d_out, int out_size, void* d_ws, size_t ws_size,
                              hipStream_t stream) {
  (void)in_sizes; (void)n_in; (void)out_size;
  const float* x   = (const float*)d_in[0];
  const float* lnw = (const float*)d_in[1];
  const float* lnb = (const float*)d_in[2];
  const float* wq  = (const float*)d_in[3];
  const float* bq  = (const float*)d_in[4];
  const float* wk  = (const float*)d_in[5];
  const float* bk  = (const float*)d_in[6];
  const float* wv  = (const float*)d_in[7];
  const float* bv  = (const float*)d_in[8];
  const float* w0  = (const float*)d_in[9];
  const float* b0  = (const float*)d_in[10];
  float* out = (float*)d_out;

  const size_t ROWS = 16384;  // B*S
  char* ws = (char*)d_ws;
  size_t off = 0;
  auto alloc = [&](size_t bytes) -> void* {
    void* p = ws + off;
    off += (bytes + 255) & ~(size_t)255;
    return p;
  };
  u16*   xn    = (u16*)alloc(ROWS * 1024 * 2);                 // 32 MB
  u16*   wqkvt = (u16*)alloc((size_t)3072 * 1024 * 2);         // 6 MB
  u16*   w0t   = (u16*)alloc((size_t)1024 * 1024 * 2);         // 2 MB
  float* bqkv  = (float*)alloc(3072 * 4);
  u16*   QKV   = (u16*)alloc(ROWS * 3072 * 2);                 // ~100.7 MB
  u16*   Wt    = (u16*)alloc(ROWS * 1024 * 2);                 // 32 MB  [8][1024][2048]

  // scores: NBCH batches of [2048 x 2048] fp32 per pass
  const size_t CHUNK1 = (size_t)2048 * 2048 * 4;  // 16 MB
  size_t avail = (ws_size > off) ? ws_size - off : 0;
  int NBCH = (int)(avail / CHUNK1);
  if (NBCH > 8) NBCH = 8;
  if (NBCH < 1) NBCH = 1;
  float* sc = (float*)(ws + off);

  ln_kernel<<<dim3(16384), dim3(256), 0, stream>>>(x, lnw, lnb, xn);
  dim3 tb(32, 8);
  transpose_w<<<dim3(32, 32), tb, 0, stream>>>(wq, wqkvt, 1024, 1024);
  transpose_w<<<dim3(32, 32), tb, 0, stream>>>(wk, wqkvt + (size_t)1024 * 1024, 1024, 1024);
  transpose_w<<<dim3(32, 32), tb, 0, stream>>>(wv, wqkvt + (size_t)2048 * 1024, 1024, 1024);
  transpose_w<<<dim3(32, 32), tb, 0, stream>>>(w0, w0t, 1024, 1024);
  concat_bias<<<dim3(3), dim3(1024), 0, stream>>>(bq, bk, bv, bqkv);

  // Fused QKV projection: [16384,1024] @ [1024,3072] -> QKV [16384,3072]
  gemm256<0, 0><<<dim3(12, 64, 1), dim3(512), 0, stream>>>(
      xn, wqkvt, QKV, bqkv, 1024, 1024, 1024, 3072, 1.0f, 0, 0, 0);

  // Wt[b][n][t] = (V[b] @ w0)[t][n]: A=w0t [1024x1024], Bt=V section of QKV
  gemm256<0, 0><<<dim3(8, 4, 8), dim3(512), 0, stream>>>(
      w0t, QKV + 2048, Wt, nullptr, 1024, 1024, 3072, 2048, 1.0f,
      0, 2048LL * 3072, 1024LL * 2048);

  float qk_scale = (float)(1.0 / (std::sqrt(1024.0) + 1e-9));
  const long long sQKV = 2048LL * 3072, sS = 2048LL * 2048, sP = 2048LL * 4096,
                  sWt = 1024LL * 2048, sH = 2048LL * 1024;

  for (int bA = 0; bA < 8; bA += NBCH) {
    int nb = 8 - bA;
    if (nb > NBCH) nb = NBCH;
    // QK^T: A=Q, B=K (both strided views into QKV), C=scores fp32
    gemm256<1, 1><<<dim3(8, 8, nb), dim3(512), 0, stream>>>(
        QKV + (size_t)bA * sQKV, QKV + (size_t)bA * sQKV + 1024, sc, nullptr,
        1024, 3072, 3072, 2048, qk_scale, sQKV, sQKV, sS);
    softmax_kernel<<<dim3(nb * 2048), dim3(256), 0, stream>>>(sc);
    // PV: A=P (bf16 in scores), Bt=Wt, C=d_out fp32 + b0
    gemm256<1, 2><<<dim3(4, 8, nb), dim3(512), 0, stream>>>(
        (const u16*)sc, Wt + (size_t)bA * sWt, out + (size_t)bA * sH, b0,
        2048, 4096, 2048, 1024, 1.0f, sP, sWt, sH);
  }
}

// Round 5
// 437.351 us; speedup vs baseline: 1.0869x; 1.0869x over previous
//
#include <hip/hip_runtime.h>
#include <cmath>

using u16 = unsigned short;
using u32 = unsigned int;
using bf16x8 = __attribute__((ext_vector_type(8))) __bf16;
using f32x4  = __attribute__((ext_vector_type(4))) float;

__device__ inline u16 f2bf(float f) {
  u32 u = __float_as_uint(f);
  u32 r = (u + 0x7fffu + ((u >> 16) & 1u)) >> 16;  // RNE
  return (u16)r;
}

// ---------------- LayerNorm: x[row][1024] f32 -> xn bf16 ----------------
__global__ __launch_bounds__(256) void ln_kernel(
    const float* __restrict__ x, const float* __restrict__ w,
    const float* __restrict__ b, u16* __restrict__ xn) {
  int row = blockIdx.x;
  const float4* xr = (const float4*)(x + (size_t)row * 1024);
  float4 v = xr[threadIdx.x];
  float s  = v.x + v.y + v.z + v.w;
  float ss = v.x * v.x + v.y * v.y + v.z * v.z + v.w * v.w;
  int lane = threadIdx.x & 63, wave = threadIdx.x >> 6;
#pragma unroll
  for (int o = 32; o >= 1; o >>= 1) {
    s  += __shfl_xor(s, o, 64);
    ss += __shfl_xor(ss, o, 64);
  }
  __shared__ float rs[4], rq[4];
  if (lane == 0) { rs[wave] = s; rq[wave] = ss; }
  __syncthreads();
  s  = rs[0] + rs[1] + rs[2] + rs[3];
  ss = rq[0] + rq[1] + rq[2] + rq[3];
  float mean = s * (1.0f / 1024.0f);
  float var  = ss * (1.0f / 1024.0f) - mean * mean;
  float rstd = rsqrtf(var + 1e-5f);
  int c = threadIdx.x * 4;
  ushort4 ov;
  ov.x = f2bf((v.x - mean) * rstd * w[c + 0] + b[c + 0]);
  ov.y = f2bf((v.y - mean) * rstd * w[c + 1] + b[c + 1]);
  ov.z = f2bf((v.z - mean) * rstd * w[c + 2] + b[c + 2]);
  ov.w = f2bf((v.w - mean) * rstd * w[c + 3] + b[c + 3]);
  ((ushort4*)(xn + (size_t)row * 1024))[threadIdx.x] = ov;
}

// ---------------- weight transpose f32 [R][C] -> bf16 [C][R] ----------------
__global__ __launch_bounds__(256) void transpose_w(
    const float* __restrict__ in, u16* __restrict__ out, int R, int C) {
  __shared__ float tile[32][33];
  int c0 = blockIdx.x * 32, r0 = blockIdx.y * 32;
  int tx = threadIdx.x, ty = threadIdx.y;  // block (32,8)
#pragma unroll
  for (int i = 0; i < 32; i += 8)
    tile[ty + i][tx] = in[(size_t)(r0 + ty + i) * C + c0 + tx];
  __syncthreads();
#pragma unroll
  for (int i = 0; i < 32; i += 8)
    out[(size_t)(c0 + ty + i) * R + r0 + tx] = f2bf(tile[tx][ty + i]);
}

// ---------------- bias concat: bq|bk|bv -> bqkv[3072] ----------------
__global__ void concat_bias(const float* __restrict__ bq, const float* __restrict__ bk,
                            const float* __restrict__ bv, float* __restrict__ o) {
  int i = blockIdx.x * 1024 + threadIdx.x;
  const float* src = (blockIdx.x == 0) ? bq : (blockIdx.x == 1) ? bk : bv;
  o[i] = src[threadIdx.x];
}

// ---------------- masked row softmax over scores fp32, writes P bf16 in-place --
__global__ __launch_bounds__(256) void softmax_kernel(float* __restrict__ scores) {
  int row = blockIdx.x;
  int s = row & 2047;
  float* srow = scores + (size_t)row * 2048;
  int tid = threadIdx.x;
  int lane = tid & 63, wave = tid >> 6;
  const float FINF = __builtin_inff();
  float x[8];
  float m = -FINF;
#pragma unroll
  for (int i = 0; i < 8; i++) {
    int t = s + tid + i * 256;
    float v = -FINF;
    if (t < 2048) {
      v = srow[t];
      v = fminf(fmaxf(v, -1.0e9f), 1.0e9f);  // CLAMP
    }
    x[i] = v;
    m = fmaxf(m, v);
  }
#pragma unroll
  for (int o = 32; o >= 1; o >>= 1) m = fmaxf(m, __shfl_xor(m, o, 64));
  __shared__ float rm[4], rsum[4];
  if (lane == 0) rm[wave] = m;
  __syncthreads();
  m = fmaxf(fmaxf(rm[0], rm[1]), fmaxf(rm[2], rm[3]));
  float sum = 0.f;
#pragma unroll
  for (int i = 0; i < 8; i++) {
    x[i] = __expf(x[i] - m);
    sum += x[i];
  }
#pragma unroll
  for (int o = 32; o >= 1; o >>= 1) sum += __shfl_xor(sum, o, 64);
  if (lane == 0) rsum[wave] = sum;
  __syncthreads();
  sum = rsum[0] + rsum[1] + rsum[2] + rsum[3];
  float inv = 1.0f / sum;
  u16* prow = (u16*)srow;
  for (int t = tid; t < s; t += 256) prow[t] = 0;
#pragma unroll
  for (int i = 0; i < 8; i++) {
    int t = s + tid + i * 256;
    if (t < 2048) prow[t] = f2bf(x[i] * inv);
  }
}

// ---------------- BMx256 8-phase bf16 GEMM body, B^T layout ----------------
// C[M,N] = A[M,K] * Bt[N,K]^T. BK=64, 8 waves (2Mx4N), wave tile (BM/2)x64.
// R3-verified schedule: half-tiles in READ-ORDER, 1 half staged per phase,
// counted vmcnt at P4/P8 (BM=256: 6 GLLs in flight; BM=128: 5), VM0 tail.
// T2 st-swizzle both-sides, T5 setprio, explicit LGKM0 before MFMA (R3).
template <int BM>
__device__ __forceinline__ void gemm_body(
    const u16* __restrict__ Ab, const u16* __restrict__ Bb,
    void* __restrict__ Cp, const float* __restrict__ bias, bool outf32,
    int K, int k0, int lda, int ldb, int ldc, float scale, size_t cbase,
    int ti, int tj, u16* __restrict__ AsP, u16* __restrict__ BsP) {
  constexpr int WM = BM / 2;    // wave tile M
  constexpr int MH = BM / 64;   // m-frags per qm half
  constexpr int FM = 2 * MH;    // m-frags per wave
  constexpr int HR = BM / 4;    // rows per A read-order half
  constexpr int LA = BM / 128;  // GLLs per thread per A half

  const int tid = threadIdx.x;
  const int wave = tid >> 6, lane = tid & 63;
  const int wr = wave >> 2, wc = wave & 3;  // 2 x 4 wave grid
  const int fr = lane & 15;
  const int kb16 = (lane >> 4) * 16;        // byte offset of k-frag in 64B k-block
  const int swz = (fr & 7) << 4;
  const int cs0 = kb16 ^ swz;               // ks=0 swizzled col byte
  const int cs1 = (64 + kb16) ^ swz;        // ks=1
  const int aRowOff = (wr * WM + fr) * 128;  // bytes
  const int bRowOff = (wc * 64 + fr) * 128;

  // Staging precompute
  size_t gAo[2][LA], gBo[2][2];
  u32 ldsA[2][LA], ldsB[2][2];
#pragma unroll
  for (int h = 0; h < 2; ++h) {
#pragma unroll
    for (int l = 0; l < LA; ++l) {
      int i = l * 512 + tid;
      int rih = i >> 3, ch8 = i & 7;
      int rA = (rih % HR) + (rih / HR) * WM + h * HR;
      int cbA = (ch8 << 4) ^ ((rA & 7) << 4);  // pre-swizzled source byte col
      gAo[h][l] = (size_t)rA * lda + (cbA >> 1);
      ldsA[h][l] = (u32)(rA * 8 + ch8) * 16;
    }
#pragma unroll
    for (int l = 0; l < 2; ++l) {
      int i = l * 512 + tid;
      int rih = i >> 3, ch8 = i & 7;
      int rB = (rih & 31) + ((rih >> 5) << 6) + h * 32;
      int cbB = (ch8 << 4) ^ ((rB & 7) << 4);
      gBo[h][l] = (size_t)rB * ldb + (cbB >> 1);
      ldsB[h][l] = (u32)(rB * 8 + ch8) * 16;
    }
  }
  const size_t aBase = (size_t)(ti * BM) * lda;
  const size_t bBase = (size_t)(tj * 256) * ldb;
  const int niter = (K - k0) / 128;  // 2 K-tiles per iteration

  f32x4 acc[FM][4] = {};
  bf16x8 aF[MH][2], bF[4][2];

#define GLL(gaddr, laddr)                                        \
  __builtin_amdgcn_global_load_lds(                              \
      (const __attribute__((address_space(1))) void*)(gaddr),    \
      (__attribute__((address_space(3))) void*)(laddr), 16, 0, 0)

#define STAGE_A(buf, h, t)                                                   \
  do {                                                                       \
    const size_t _kt = aBase + (size_t)(k0 + (t) * 64);                      \
    _Pragma("unroll") for (int _l = 0; _l < LA; ++_l)                        \
        GLL(Ab + _kt + gAo[h][_l],                                           \
            (char*)(AsP + (buf) * (BM * 64)) + ldsA[h][_l]);                 \
  } while (0)
#define STAGE_B(buf, h, t)                                                   \
  do {                                                                       \
    const size_t _kt = bBase + (size_t)(k0 + (t) * 64);                      \
    _Pragma("unroll") for (int _l = 0; _l < 2; ++_l)                         \
        GLL(Bb + _kt + gBo[h][_l],                                           \
            (char*)(BsP + (buf) * (256 * 64)) + ldsB[h][_l]);                \
  } while (0)

#define DS_A(buf, qm)                                                        \
  do {                                                                       \
    const char* _pa =                                                        \
        (const char*)(AsP + (buf) * (BM * 64)) + aRowOff + (qm) * (MH * 2048); \
    _Pragma("unroll") for (int mm = 0; mm < MH; ++mm) {                      \
      aF[mm][0] = *(const bf16x8*)(_pa + mm * 2048 + cs0);                   \
      aF[mm][1] = *(const bf16x8*)(_pa + mm * 2048 + cs1);                   \
    }                                                                        \
  } while (0)
#define DS_B(buf, nh)                                                        \
  do {                                                                       \
    const char* _pb = (const char*)(BsP + (buf) * (256 * 64)) + bRowOff;     \
    _Pragma("unroll") for (int nn = 0; nn < 2; ++nn) {                       \
      bF[(nh)*2 + nn][0] = *(const bf16x8*)(_pb + ((nh)*2 + nn) * 2048 + cs0); \
      bF[(nh)*2 + nn][1] = *(const bf16x8*)(_pb + ((nh)*2 + nn) * 2048 + cs1); \
    }                                                                        \
  } while (0)

#define MMA(qm, nh)                                                          \
  do {                                                                       \
    _Pragma("unroll") for (int mm = 0; mm < MH; ++mm)                        \
    _Pragma("unroll") for (int nn = 0; nn < 2; ++nn) {                       \
      f32x4 _c = acc[(qm)*MH + mm][(nh)*2 + nn];                             \
      _c = __builtin_amdgcn_mfma_f32_16x16x32_bf16(aF[mm][0], bF[(nh)*2+nn][0], _c, 0, 0, 0); \
      _c = __builtin_amdgcn_mfma_f32_16x16x32_bf16(aF[mm][1], bF[(nh)*2+nn][1], _c, 0, 0, 0); \
      acc[(qm)*MH + mm][(nh)*2 + nn] = _c;                                   \
    }                                                                        \
  } while (0)

#define BAR __builtin_amdgcn_s_barrier()
#define LGKM0 asm volatile("s_waitcnt lgkmcnt(0)" ::: "memory")
#define VMN                                                                  \
  do {                                                                       \
    if constexpr (BM == 256)                                                 \
      asm volatile("s_waitcnt vmcnt(6)" ::: "memory");                       \
    else                                                                     \
      asm volatile("s_waitcnt vmcnt(5)" ::: "memory");                       \
  } while (0)
#define VM0 asm volatile("s_waitcnt vmcnt(0)" ::: "memory")
#define PRIO1 __builtin_amdgcn_s_setprio(1)
#define PRIO0 __builtin_amdgcn_s_setprio(0)

  // Prologue: tile0 all 4 halves (read-order) + tile1 B-h0,B-h1,A-h0.
  STAGE_B(0, 0, 0); STAGE_B(0, 1, 0); STAGE_A(0, 0, 0); STAGE_A(0, 1, 0);
  STAGE_B(1, 0, 1); STAGE_B(1, 1, 1); STAGE_A(1, 0, 1);
  VMN; BAR;  // tile0 fully landed; 3 half-tiles (tile1 B+A-h0) in flight

  for (int it = 0; it < niter; ++it) {
    const bool last = (it == niter - 1);
    const int t1g = 2 * it + 1, t2g = 2 * it + 2, t3g = 2 * it + 3;

    // ---- P1: read buf0 qm0+nh0; stage A-h1(t1g)->buf1
    DS_A(0, 0); DS_B(0, 0);
    STAGE_A(1, 1, t1g);
    BAR; LGKM0; PRIO1; MMA(0, 0); PRIO0; BAR;
    // ---- P2: read buf0 nh1; stage B-h0(t2g)->buf0
    DS_B(0, 1);
    if (!last) STAGE_B(0, 0, t2g);
    BAR; LGKM0; PRIO1; MMA(0, 1); PRIO0; BAR;
    // ---- P3: read buf0 qm1; stage B-h1(t2g)
    DS_A(0, 1);
    if (!last) STAGE_B(0, 1, t2g);
    BAR; LGKM0; PRIO1; MMA(1, 0); PRIO0; BAR;
    // ---- P4: stage A-h0(t2g); K-tile wait (lands ALL of tile t1g)
    if (!last) STAGE_A(0, 0, t2g);
    BAR; PRIO1; MMA(1, 1); PRIO0;
    if (last) { VM0; } else { VMN; }
    BAR;
    // ---- P5: read buf1 qm0+nh0; stage A-h1(t2g)
    DS_A(1, 0); DS_B(1, 0);
    if (!last) STAGE_A(0, 1, t2g);
    BAR; LGKM0; PRIO1; MMA(0, 0); PRIO0; BAR;
    // ---- P6: read buf1 nh1; stage B-h0(t3g)->buf1
    DS_B(1, 1);
    if (!last) STAGE_B(1, 0, t3g);
    BAR; LGKM0; PRIO1; MMA(0, 1); PRIO0; BAR;
    // ---- P7: read buf1 qm1; stage B-h1(t3g)
    DS_A(1, 1);
    if (!last) STAGE_B(1, 1, t3g);
    BAR; LGKM0; PRIO1; MMA(1, 0); PRIO0; BAR;
    // ---- P8: stage A-h0(t3g); K-tile wait (lands ALL of tile t2g)
    if (!last) STAGE_A(1, 0, t3g);
    BAR; PRIO1; MMA(1, 1); PRIO0;
    if (!last) VMN;
    BAR;
  }

  // Epilogue: C/D layout col=lane&15, row=(lane>>4)*4+j
  const int orow0 = ti * BM + wr * WM + ((lane >> 4) << 2);
  const int ocol0 = tj * 256 + wc * 64 + fr;
#pragma unroll
  for (int m = 0; m < FM; ++m) {
#pragma unroll
    for (int n = 0; n < 4; ++n) {
      const int col = ocol0 + n * 16;
      const float bv = bias ? bias[col] : 0.0f;
#pragma unroll
      for (int j = 0; j < 4; ++j) {
        const int row = orow0 + m * 16 + j;
        const float v = acc[m][n][j] * scale + bv;
        const size_t idx = cbase + (size_t)row * ldc + col;
        if (outf32) ((float*)Cp)[idx] = v;
        else        ((u16*)Cp)[idx]   = f2bf(v);
      }
    }
  }
#undef GLL
#undef STAGE_A
#undef STAGE_B
#undef DS_A
#undef DS_B
#undef MMA
#undef BAR
#undef LGKM0
#undef VMN
#undef VM0
#undef PRIO1
#undef PRIO0
}

// ---------------- plain wrapper (QKV projection), XCD-swizzled grid ---------
template <int BM>
__global__ __launch_bounds__(512, 2) void gemm_plain(
    const u16* __restrict__ A, const u16* __restrict__ B, void* __restrict__ Cv,
    const float* __restrict__ bias, int outf32, int K, int lda, int ldb,
    int ldc, float scale, long long sA, long long sB, long long sC) {
  __shared__ u16 As[2][BM * 64];
  __shared__ u16 Bs[2][256 * 64];
  int gx = gridDim.x;
  int wg = blockIdx.y * gx + blockIdx.x;
  int nwg = gx * gridDim.y;
  if ((nwg & 7) == 0) { int q = nwg >> 3; wg = (wg & 7) * q + (wg >> 3); }
  const int ti = wg / gx, tj = wg % gx, bz = blockIdx.z;
  gemm_body<BM>(A + (size_t)bz * sA, B + (size_t)bz * sB, Cv, bias,
                outf32 != 0, K, 0, lda, ldb, ldc, scale, (size_t)bz * sC,
                ti, tj, &As[0][0], &Bs[0][0]);
}

// ---------------- combined QK^T + Wt dispatch (BM=128) ----------------------
// x < wtBlocks: Wt[bz][e][t] = sum_d w0t[e][d] * V[bz][t][d]  (bf16 out)
// else: QK tile, triangular decode (skip fully-masked), fp32 scores out.
__global__ __launch_bounds__(512, 2) void gemm_qkwt(
    const u16* __restrict__ QKVp, const u16* __restrict__ w0t,
    u16* __restrict__ Wt, float* __restrict__ sc, int wtBlocks, int b0,
    float qk_scale) {
  __shared__ u16 As[2][128 * 64];
  __shared__ u16 Bs[2][256 * 64];
  const long long sQKV = 2048LL * 3072, sWt = 1024LL * 2048, sS = 2048LL * 2048;
  int x = blockIdx.x;
  const u16 *Ab, *Bb;
  void* Cp;
  bool outf32;
  int lda, ldb, ldc, ti, tj;
  float scale;
  size_t cbase;
  if (x < wtBlocks) {
    int bz = x >> 6, r = x & 63;
    ti = r & 7; tj = r >> 3;
    Ab = w0t; lda = 1024;
    Bb = QKVp + (size_t)bz * sQKV + 2048; ldb = 3072;
    Cp = Wt; ldc = 2048; cbase = (size_t)bz * sWt;
    outf32 = false; scale = 1.0f;
  } else {
    int q = x - wtBlocks;
    int bz = b0 + q / 72, t = q % 72;
    ti = 0;
    for (;;) { int L = 8 - (ti >> 1); if (t < L) break; t -= L; ++ti; }
    tj = (ti >> 1) + t;
    Ab = QKVp + (size_t)bz * sQKV; lda = 3072;
    Bb = Ab + 1024; ldb = 3072;
    Cp = sc; ldc = 2048; cbase = (size_t)(bz - b0) * sS;
    outf32 = true; scale = qk_scale;
  }
  gemm_body<128>(Ab, Bb, Cp, nullptr, outf32, 1024, 0, lda, ldb, ldc, scale,
                 cbase, ti, tj, &As[0][0], &Bs[0][0]);
}

// ---------------- PV dispatch (BM=128), LPT ti-major ordering ----------------
// out[bz][s][e] = sum_t P[bz][s][t] * Wt[bz][e][t] + b0[e]; k0 = ti*128.
__global__ __launch_bounds__(512, 2) void gemm_pv(
    const u16* __restrict__ sc, const u16* __restrict__ Wt,
    float* __restrict__ out, const float* __restrict__ b0v, int nb, int bA) {
  __shared__ u16 As[2][128 * 64];
  __shared__ u16 Bs[2][256 * 64];
  const long long sP = 2048LL * 4096, sWt = 1024LL * 2048, sH = 2048LL * 1024;
  int x = blockIdx.x;
  int g = 4 * nb;
  int ti = x / g, r = x % g;
  int bzl = r >> 2, tj = r & 3;
  int bz = bA + bzl;
  gemm_body<128>(sc + (size_t)bzl * sP, Wt + (size_t)bz * sWt, out, b0v, true,
                 2048, ti * 128, 4096, 2048, 1024, 1.0f, (size_t)bz * sH,
                 ti, tj, &As[0][0], &Bs[0][0]);
}

extern "C" void kernel_launch(void* const* d_in, const int* in_sizes, int n_in,
                              void* d_out, int out_size, void* d_ws, size_t ws_size,
                              hipStream_t stream) {
  (void)in_sizes; (void)n_in; (void)out_size;
  const float* x   = (const float*)d_in[0];
  const float* lnw = (const float*)d_in[1];
  const float* lnb = (const float*)d_in[2];
  const float* wq  = (const float*)d_in[3];
  const float* bq  = (const float*)d_in[4];
  const float* wk  = (const float*)d_in[5];
  const float* bk  = (const float*)d_in[6];
  const float* wv  = (const float*)d_in[7];
  const float* bv  = (const float*)d_in[8];
  const float* w0  = (const float*)d_in[9];
  const float* b0  = (const float*)d_in[10];
  float* out = (float*)d_out;

  const size_t ROWS = 16384;  // B*S
  char* ws = (char*)d_ws;
  size_t off = 0;
  auto alloc = [&](size_t bytes) -> void* {
    void* p = ws + off;
    off += (bytes + 255) & ~(size_t)255;
    return p;
  };
  u16*   xn    = (u16*)alloc(ROWS * 1024 * 2);          // 32 MB
  u16*   wqkvt = (u16*)alloc((size_t)3072 * 1024 * 2);  // 6 MB
  u16*   w0t   = (u16*)alloc((size_t)1024 * 1024 * 2);  // 2 MB
  float* bqkv  = (float*)alloc(3072 * 4);
  u16*   QKV   = (u16*)alloc(ROWS * 3072 * 2);          // ~100.7 MB
  u16*   Wt    = (u16*)alloc(ROWS * 1024 * 2);          // 32 MB [8][1024][2048]

  // scores: NBCH batches of [2048 x 2048] fp32 per pass
  const size_t CHUNK1 = (size_t)2048 * 2048 * 4;  // 16 MB
  size_t avail = (ws_size > off) ? ws_size - off : 0;
  int NBCH = (int)(avail / CHUNK1);
  if (NBCH > 8) NBCH = 8;
  if (NBCH < 1) NBCH = 1;
  float* sc = (float*)(ws + off);

  ln_kernel<<<dim3(16384), dim3(256), 0, stream>>>(x, lnw, lnb, xn);
  dim3 tb(32, 8);
  transpose_w<<<dim3(32, 32), tb, 0, stream>>>(wq, wqkvt, 1024, 1024);
  transpose_w<<<dim3(32, 32), tb, 0, stream>>>(wk, wqkvt + (size_t)1024 * 1024, 1024, 1024);
  transpose_w<<<dim3(32, 32), tb, 0, stream>>>(wv, wqkvt + (size_t)2048 * 1024, 1024, 1024);
  transpose_w<<<dim3(32, 32), tb, 0, stream>>>(w0, w0t, 1024, 1024);
  concat_bias<<<dim3(3), dim3(1024), 0, stream>>>(bq, bk, bv, bqkv);

  // Fused QKV projection: [16384,1024] @ [1024,3072] -> QKV (BM=256 path)
  gemm_plain<256><<<dim3(12, 64, 1), dim3(512), 0, stream>>>(
      xn, wqkvt, QKV, bqkv, 0, 1024, 1024, 1024, 3072, 1.0f, 0, 0, 0);

  float qk_scale = (float)(1.0 / (std::sqrt(1024.0) + 1e-9));

  for (int bA = 0; bA < 8; bA += NBCH) {
    int nb = 8 - bA;
    if (nb > NBCH) nb = NBCH;
    int wtB = (bA == 0) ? 512 : 0;  // Wt for ALL batches rides the first pass
    gemm_qkwt<<<dim3(wtB + nb * 72), dim3(512), 0, stream>>>(
        QKV, w0t, Wt, sc, wtB, bA, qk_scale);
    softmax_kernel<<<dim3(nb * 2048), dim3(256), 0, stream>>>(sc);
    gemm_pv<<<dim3(64 * nb), dim3(512), 0, stream>>>(
        (const u16*)sc, Wt, out, b0, nb, bA);
  }
}

// Round 6
// 379.859 us; speedup vs baseline: 1.2514x; 1.1514x over previous
//
#include <hip/hip_runtime.h>
#include <cmath>

using u16 = unsigned short;
using u32 = unsigned int;
using bf16x8 = __attribute__((ext_vector_type(8))) __bf16;
using f32x4  = __attribute__((ext_vector_type(4))) float;

__device__ inline u16 f2bf(float f) {
  u32 u = __float_as_uint(f);
  u32 r = (u + 0x7fffu + ((u >> 16) & 1u)) >> 16;  // RNE
  return (u16)r;
}
__device__ inline float bf2f(u16 v) {
  u32 u = ((u32)v) << 16;
  return __uint_as_float(u);
}

// ---------------- LayerNorm: x[row][1024] f32 -> xn bf16 ----------------
__global__ __launch_bounds__(256) void ln_kernel(
    const float* __restrict__ x, const float* __restrict__ w,
    const float* __restrict__ b, u16* __restrict__ xn) {
  int row = blockIdx.x;
  const float4* xr = (const float4*)(x + (size_t)row * 1024);
  float4 v = xr[threadIdx.x];
  float s  = v.x + v.y + v.z + v.w;
  float ss = v.x * v.x + v.y * v.y + v.z * v.z + v.w * v.w;
  int lane = threadIdx.x & 63, wave = threadIdx.x >> 6;
#pragma unroll
  for (int o = 32; o >= 1; o >>= 1) {
    s  += __shfl_xor(s, o, 64);
    ss += __shfl_xor(ss, o, 64);
  }
  __shared__ float rs[4], rq[4];
  if (lane == 0) { rs[wave] = s; rq[wave] = ss; }
  __syncthreads();
  s  = rs[0] + rs[1] + rs[2] + rs[3];
  ss = rq[0] + rq[1] + rq[2] + rq[3];
  float mean = s * (1.0f / 1024.0f);
  float var  = ss * (1.0f / 1024.0f) - mean * mean;
  float rstd = rsqrtf(var + 1e-5f);
  int c = threadIdx.x * 4;
  ushort4 ov;
  ov.x = f2bf((v.x - mean) * rstd * w[c + 0] + b[c + 0]);
  ov.y = f2bf((v.y - mean) * rstd * w[c + 1] + b[c + 1]);
  ov.z = f2bf((v.z - mean) * rstd * w[c + 2] + b[c + 2]);
  ov.w = f2bf((v.w - mean) * rstd * w[c + 3] + b[c + 3]);
  ((ushort4*)(xn + (size_t)row * 1024))[threadIdx.x] = ov;
}

// ---------------- weight transpose f32 [R][C] -> bf16 [C][R] ----------------
__global__ __launch_bounds__(256) void transpose_w(
    const float* __restrict__ in, u16* __restrict__ out, int R, int C) {
  __shared__ float tile[32][33];
  int c0 = blockIdx.x * 32, r0 = blockIdx.y * 32;
  int tx = threadIdx.x, ty = threadIdx.y;  // block (32,8)
#pragma unroll
  for (int i = 0; i < 32; i += 8)
    tile[ty + i][tx] = in[(size_t)(r0 + ty + i) * C + c0 + tx];
  __syncthreads();
#pragma unroll
  for (int i = 0; i < 32; i += 8)
    out[(size_t)(c0 + ty + i) * R + r0 + tx] = f2bf(tile[tx][ty + i]);
}

// ---------------- bias concat: bq|bk|bv -> bqkv[3072] ----------------
__global__ void concat_bias(const float* __restrict__ bq, const float* __restrict__ bk,
                            const float* __restrict__ bv, float* __restrict__ o) {
  int i = blockIdx.x * 1024 + threadIdx.x;
  const float* src = (blockIdx.x == 0) ? bq : (blockIdx.x == 1) ? bk : bv;
  o[i] = src[threadIdx.x];
}

// ------------- masked row softmax over bf16 scores, in-place, uses pmax ------
// Row s: valid t in [s,2047]. Max comes from pmax partials (written by QK).
// Zeros written only over [s&~127, s) — the only masked region PV reads.
__global__ __launch_bounds__(256) void softmax_kernel(
    u16* __restrict__ scores, const float* __restrict__ pmax, int bA) {
  int row = blockIdx.x;
  int bzl = row >> 11, s = row & 2047;
  int bz = bA + bzl;
  u16* srow = scores + (size_t)bzl * 2048 * 2048 + (size_t)s * 2048;
  int tid = threadIdx.x;
  int lane = tid & 63, wave = tid >> 6;
  float m = -__builtin_inff();
  for (int tj = (s >> 8); tj < 8; ++tj)
    m = fmaxf(m, pmax[((size_t)bz * 8 + tj) * 2048 + s]);
  const int base = s & ~127;
  float x[8];
  float sum = 0.f;
#pragma unroll
  for (int i = 0; i < 8; i++) {
    int t = base + tid + i * 256;
    float e = 0.f;
    if (t >= s && t < 2048) e = __expf(bf2f(srow[t]) - m);
    x[i] = e;
    sum += e;
  }
#pragma unroll
  for (int o = 32; o >= 1; o >>= 1) sum += __shfl_xor(sum, o, 64);
  __shared__ float rsum[4];
  if (lane == 0) rsum[wave] = sum;
  __syncthreads();
  sum = rsum[0] + rsum[1] + rsum[2] + rsum[3];
  float inv = 1.0f / sum;
#pragma unroll
  for (int i = 0; i < 8; i++) {
    int t = base + tid + i * 256;
    if (t < 2048) srow[t] = (t >= s) ? f2bf(x[i] * inv) : (u16)0;
  }
}

// ---------------- BMx256 8-phase bf16 GEMM body, B^T layout ----------------
// C[M,N] = A[M,K] * Bt[N,K]^T. BK=64, 8 waves (2Mx4N), wave tile (BM/2)x64.
// R3-verified schedule: half-tiles in READ-ORDER, 1 half staged per phase,
// counted vmcnt at P4/P8 (BM=256: 6 GLLs in flight; BM=128: 5), VM0 tail.
// T2 st-swizzle both-sides, T5 setprio, explicit LGKM0 before MFMA.
// pmaxRow != null (QK): clamp scores, write bf16, store per-row tile max.
template <int BM, int OUTF32>
__device__ __forceinline__ void gemm_body(
    const u16* __restrict__ Ab, const u16* __restrict__ Bb,
    void* __restrict__ Cp, const float* __restrict__ bias,
    int K, int k0, int lda, int ldb, int ldc, float scale, size_t cbase,
    int ti, int tj, u16* __restrict__ AsP, u16* __restrict__ BsP,
    float* __restrict__ pmaxRow) {
  constexpr int WM = BM / 2;    // wave tile M
  constexpr int MH = BM / 64;   // m-frags per qm half
  constexpr int FM = 2 * MH;    // m-frags per wave
  constexpr int HR = BM / 4;    // rows per A read-order half
  constexpr int LA = BM / 128;  // GLLs per thread per A half

  const int tid = threadIdx.x;
  const int wave = tid >> 6, lane = tid & 63;
  const int wr = wave >> 2, wc = wave & 3;  // 2 x 4 wave grid
  const int fr = lane & 15;
  const int kb16 = (lane >> 4) * 16;        // byte offset of k-frag in 64B k-block
  const int swz = (fr & 7) << 4;
  const int cs0 = kb16 ^ swz;               // ks=0 swizzled col byte
  const int cs1 = (64 + kb16) ^ swz;        // ks=1
  const int aRowOff = (wr * WM + fr) * 128;  // bytes
  const int bRowOff = (wc * 64 + fr) * 128;

  // Staging precompute
  size_t gAo[2][LA], gBo[2][2];
  u32 ldsA[2][LA], ldsB[2][2];
#pragma unroll
  for (int h = 0; h < 2; ++h) {
#pragma unroll
    for (int l = 0; l < LA; ++l) {
      int i = l * 512 + tid;
      int rih = i >> 3, ch8 = i & 7;
      int rA = (rih % HR) + (rih / HR) * WM + h * HR;
      int cbA = (ch8 << 4) ^ ((rA & 7) << 4);  // pre-swizzled source byte col
      gAo[h][l] = (size_t)rA * lda + (cbA >> 1);
      ldsA[h][l] = (u32)(rA * 8 + ch8) * 16;
    }
#pragma unroll
    for (int l = 0; l < 2; ++l) {
      int i = l * 512 + tid;
      int rih = i >> 3, ch8 = i & 7;
      int rB = (rih & 31) + ((rih >> 5) << 6) + h * 32;
      int cbB = (ch8 << 4) ^ ((rB & 7) << 4);
      gBo[h][l] = (size_t)rB * ldb + (cbB >> 1);
      ldsB[h][l] = (u32)(rB * 8 + ch8) * 16;
    }
  }
  const size_t aBase = (size_t)(ti * BM) * lda;
  const size_t bBase = (size_t)(tj * 256) * ldb;
  const int niter = (K - k0) / 128;  // 2 K-tiles per iteration

  f32x4 acc[FM][4] = {};
  bf16x8 aF[MH][2], bF[4][2];

#define GLL(gaddr, laddr)                                        \
  __builtin_amdgcn_global_load_lds(                              \
      (const __attribute__((address_space(1))) void*)(gaddr),    \
      (__attribute__((address_space(3))) void*)(laddr), 16, 0, 0)

#define STAGE_A(buf, h, t)                                                   \
  do {                                                                       \
    const size_t _kt = aBase + (size_t)(k0 + (t) * 64);                      \
    _Pragma("unroll") for (int _l = 0; _l < LA; ++_l)                        \
        GLL(Ab + _kt + gAo[h][_l],                                           \
            (char*)(AsP + (buf) * (BM * 64)) + ldsA[h][_l]);                 \
  } while (0)
#define STAGE_B(buf, h, t)                                                   \
  do {                                                                       \
    const size_t _kt = bBase + (size_t)(k0 + (t) * 64);                      \
    _Pragma("unroll") for (int _l = 0; _l < 2; ++_l)                         \
        GLL(Bb + _kt + gBo[h][_l],                                           \
            (char*)(BsP + (buf) * (256 * 64)) + ldsB[h][_l]);                \
  } while (0)

#define DS_A(buf, qm)                                                        \
  do {                                                                       \
    const char* _pa =                                                        \
        (const char*)(AsP + (buf) * (BM * 64)) + aRowOff + (qm) * (MH * 2048); \
    _Pragma("unroll") for (int mm = 0; mm < MH; ++mm) {                      \
      aF[mm][0] = *(const bf16x8*)(_pa + mm * 2048 + cs0);                   \
      aF[mm][1] = *(const bf16x8*)(_pa + mm * 2048 + cs1);                   \
    }                                                                        \
  } while (0)
#define DS_B(buf, nh)                                                        \
  do {                                                                       \
    const char* _pb = (const char*)(BsP + (buf) * (256 * 64)) + bRowOff;     \
    _Pragma("unroll") for (int nn = 0; nn < 2; ++nn) {                       \
      bF[(nh)*2 + nn][0] = *(const bf16x8*)(_pb + ((nh)*2 + nn) * 2048 + cs0); \
      bF[(nh)*2 + nn][1] = *(const bf16x8*)(_pb + ((nh)*2 + nn) * 2048 + cs1); \
    }                                                                        \
  } while (0)

#define MMA(qm, nh)                                                          \
  do {                                                                       \
    _Pragma("unroll") for (int mm = 0; mm < MH; ++mm)                        \
    _Pragma("unroll") for (int nn = 0; nn < 2; ++nn) {                       \
      f32x4 _c = acc[(qm)*MH + mm][(nh)*2 + nn];                             \
      _c = __builtin_amdgcn_mfma_f32_16x16x32_bf16(aF[mm][0], bF[(nh)*2+nn][0], _c, 0, 0, 0); \
      _c = __builtin_amdgcn_mfma_f32_16x16x32_bf16(aF[mm][1], bF[(nh)*2+nn][1], _c, 0, 0, 0); \
      acc[(qm)*MH + mm][(nh)*2 + nn] = _c;                                   \
    }                                                                        \
  } while (0)

#define BAR __builtin_amdgcn_s_barrier()
#define LGKM0 asm volatile("s_waitcnt lgkmcnt(0)" ::: "memory")
#define VMN                                                                  \
  do {                                                                       \
    if constexpr (BM == 256)                                                 \
      asm volatile("s_waitcnt vmcnt(6)" ::: "memory");                       \
    else                                                                     \
      asm volatile("s_waitcnt vmcnt(5)" ::: "memory");                       \
  } while (0)
#define VM0 asm volatile("s_waitcnt vmcnt(0)" ::: "memory")
#define PRIO1 __builtin_amdgcn_s_setprio(1)
#define PRIO0 __builtin_amdgcn_s_setprio(0)

  // Prologue: tile0 all 4 halves (read-order) + tile1 B-h0,B-h1,A-h0.
  STAGE_B(0, 0, 0); STAGE_B(0, 1, 0); STAGE_A(0, 0, 0); STAGE_A(0, 1, 0);
  STAGE_B(1, 0, 1); STAGE_B(1, 1, 1); STAGE_A(1, 0, 1);
  VMN; BAR;  // tile0 fully landed; 3 half-tiles (tile1 B+A-h0) in flight

  for (int it = 0; it < niter; ++it) {
    const bool last = (it == niter - 1);
    const int t1g = 2 * it + 1, t2g = 2 * it + 2, t3g = 2 * it + 3;

    // ---- P1: read buf0 qm0+nh0; stage A-h1(t1g)->buf1
    DS_A(0, 0); DS_B(0, 0);
    STAGE_A(1, 1, t1g);
    BAR; LGKM0; PRIO1; MMA(0, 0); PRIO0; BAR;
    // ---- P2: read buf0 nh1; stage B-h0(t2g)->buf0
    DS_B(0, 1);
    if (!last) STAGE_B(0, 0, t2g);
    BAR; LGKM0; PRIO1; MMA(0, 1); PRIO0; BAR;
    // ---- P3: read buf0 qm1; stage B-h1(t2g)
    DS_A(0, 1);
    if (!last) STAGE_B(0, 1, t2g);
    BAR; LGKM0; PRIO1; MMA(1, 0); PRIO0; BAR;
    // ---- P4: stage A-h0(t2g); K-tile wait (lands ALL of tile t1g)
    if (!last) STAGE_A(0, 0, t2g);
    BAR; PRIO1; MMA(1, 1); PRIO0;
    if (last) { VM0; } else { VMN; }
    BAR;
    // ---- P5: read buf1 qm0+nh0; stage A-h1(t2g)
    DS_A(1, 0); DS_B(1, 0);
    if (!last) STAGE_A(0, 1, t2g);
    BAR; LGKM0; PRIO1; MMA(0, 0); PRIO0; BAR;
    // ---- P6: read buf1 nh1; stage B-h0(t3g)->buf1
    DS_B(1, 1);
    if (!last) STAGE_B(1, 0, t3g);
    BAR; LGKM0; PRIO1; MMA(0, 1); PRIO0; BAR;
    // ---- P7: read buf1 qm1; stage B-h1(t3g)
    DS_A(1, 1);
    if (!last) STAGE_B(1, 1, t3g);
    BAR; LGKM0; PRIO1; MMA(1, 0); PRIO0; BAR;
    // ---- P8: stage A-h0(t3g); K-tile wait (lands ALL of tile t2g)
    if (!last) STAGE_A(1, 0, t3g);
    BAR; PRIO1; MMA(1, 1); PRIO0;
    if (!last) VMN;
    BAR;
  }

  // Epilogue: C/D layout col=lane&15, row=(lane>>4)*4+j
  const int orow0 = ti * BM + wr * WM + ((lane >> 4) << 2);
  const int ocol0 = tj * 256 + wc * 64 + fr;
#pragma unroll
  for (int m = 0; m < FM; ++m) {
    float rmax[4] = {-3.0e38f, -3.0e38f, -3.0e38f, -3.0e38f};
#pragma unroll
    for (int n = 0; n < 4; ++n) {
      const int col = ocol0 + n * 16;
      const float bv = bias ? bias[col] : 0.0f;
#pragma unroll
      for (int j = 0; j < 4; ++j) {
        const int row = orow0 + m * 16 + j;
        float v = acc[m][n][j] * scale + bv;
        if (pmaxRow) {
          v = fminf(fmaxf(v, -1.0e9f), 1.0e9f);  // CLAMP (scores)
          rmax[j] = fmaxf(rmax[j], v);
        }
        const size_t idx = cbase + (size_t)row * ldc + col;
        if (OUTF32) ((float*)Cp)[idx] = v;
        else        ((u16*)Cp)[idx]   = f2bf(v);
      }
    }
    if (pmaxRow) {
#pragma unroll
      for (int j = 0; j < 4; ++j) {
        float r = rmax[j];
        r = fmaxf(r, __shfl_xor(r, 1, 64));
        r = fmaxf(r, __shfl_xor(r, 2, 64));
        r = fmaxf(r, __shfl_xor(r, 4, 64));
        r = fmaxf(r, __shfl_xor(r, 8, 64));
        if (fr == 0) pmaxRow[orow0 + m * 16 + j] = r;
      }
    }
  }
#undef GLL
#undef STAGE_A
#undef STAGE_B
#undef DS_A
#undef DS_B
#undef MMA
#undef BAR
#undef LGKM0
#undef VMN
#undef VM0
#undef PRIO1
#undef PRIO0
}

// ---------------- plain wrapper (QKV projection), XCD-swizzled grid ---------
__global__ __launch_bounds__(512, 2) void gemm_qkv(
    const u16* __restrict__ A, const u16* __restrict__ B, u16* __restrict__ Cv,
    const float* __restrict__ bias) {
  __shared__ u16 As[2][256 * 64];
  __shared__ u16 Bs[2][256 * 64];
  int gx = gridDim.x;
  int wg = blockIdx.y * gx + blockIdx.x;
  int nwg = gx * gridDim.y;
  if ((nwg & 7) == 0) { int q = nwg >> 3; wg = (wg & 7) * q + (wg >> 3); }
  const int ti = wg / gx, tj = wg % gx;
  gemm_body<256, 0>(A, B, Cv, bias, 1024, 0, 1024, 1024, 3072, 1.0f, 0,
                    ti, tj, &As[0][0], &Bs[0][0], nullptr);
}

// ---------------- combined QK^T + Wt dispatch (BM=128) ----------------------
// x < wtBlocks: Wt[bz][e][t] = sum_d w0t[e][d] * V[bz][t][d]  (bf16 out)
// else: QK tile (bf16 scores + pmax partials), triangular decode.
__global__ __launch_bounds__(512, 2) void gemm_qkwt(
    const u16* __restrict__ QKVp, const u16* __restrict__ w0t,
    u16* __restrict__ Wt, u16* __restrict__ sc, float* __restrict__ pmax,
    int wtBlocks, int b0, float qk_scale) {
  __shared__ u16 As[2][128 * 64];
  __shared__ u16 Bs[2][256 * 64];
  const long long sQKV = 2048LL * 3072, sWt = 1024LL * 2048, sS = 2048LL * 2048;
  int x = blockIdx.x;
  if (x < wtBlocks) {
    int bz = x >> 6, r = x & 63;
    int ti = r & 7, tj = r >> 3;
    gemm_body<128, 0>(w0t, QKVp + (size_t)bz * sQKV + 2048, Wt, nullptr,
                      1024, 0, 1024, 3072, 2048, 1.0f, (size_t)bz * sWt,
                      ti, tj, &As[0][0], &Bs[0][0], nullptr);
  } else {
    int q = x - wtBlocks;
    int bz = b0 + q / 72, t = q % 72;
    int ti = 0;
    for (;;) { int L = 8 - (ti >> 1); if (t < L) break; t -= L; ++ti; }
    int tj = (ti >> 1) + t;
    const u16* Ab = QKVp + (size_t)bz * sQKV;
    float* pmr = pmax + ((size_t)bz * 8 + tj) * 2048;
    gemm_body<128, 0>(Ab, Ab + 1024, sc, nullptr, 1024, 0, 3072, 3072, 2048,
                      qk_scale, (size_t)(bz - b0) * sS, ti, tj,
                      &As[0][0], &Bs[0][0], pmr);
  }
}

// ---------------- PV dispatch (BM=128), LPT ti-major ordering ----------------
// out[bz][s][e] = sum_t P[bz][s][t] * Wt[bz][e][t] + b0[e]; k0 = ti*128.
__global__ __launch_bounds__(512, 2) void gemm_pv(
    const u16* __restrict__ sc, const u16* __restrict__ Wt,
    float* __restrict__ out, const float* __restrict__ b0v, int nb, int bA) {
  __shared__ u16 As[2][128 * 64];
  __shared__ u16 Bs[2][256 * 64];
  const long long sP = 2048LL * 2048, sWt = 1024LL * 2048, sH = 2048LL * 1024;
  int x = blockIdx.x;
  int g = 4 * nb;
  int ti = x / g, r = x % g;
  int bzl = r >> 2, tj = r & 3;
  int bz = bA + bzl;
  gemm_body<128, 1>(sc + (size_t)bzl * sP, Wt + (size_t)bz * sWt, out, b0v,
                    2048, ti * 128, 2048, 2048, 1024, 1.0f, (size_t)bz * sH,
                    ti, tj, &As[0][0], &Bs[0][0], nullptr);
}

extern "C" void kernel_launch(void* const* d_in, const int* in_sizes, int n_in,
                              void* d_out, int out_size, void* d_ws, size_t ws_size,
                              hipStream_t stream) {
  (void)in_sizes; (void)n_in; (void)out_size;
  const float* x   = (const float*)d_in[0];
  const float* lnw = (const float*)d_in[1];
  const float* lnb = (const float*)d_in[2];
  const float* wq  = (const float*)d_in[3];
  const float* bq  = (const float*)d_in[4];
  const float* wk  = (const float*)d_in[5];
  const float* bk  = (const float*)d_in[6];
  const float* wv  = (const float*)d_in[7];
  const float* bv  = (const float*)d_in[8];
  const float* w0  = (const float*)d_in[9];
  const float* b0  = (const float*)d_in[10];
  float* out = (float*)d_out;

  const size_t ROWS = 16384;  // B*S
  char* ws = (char*)d_ws;
  size_t off = 0;
  auto alloc = [&](size_t bytes) -> void* {
    void* p = ws + off;
    off += (bytes + 255) & ~(size_t)255;
    return p;
  };
  u16*   xn    = (u16*)alloc(ROWS * 1024 * 2);          // 32 MB
  u16*   wqkvt = (u16*)alloc((size_t)3072 * 1024 * 2);  // 6 MB
  u16*   w0t   = (u16*)alloc((size_t)1024 * 1024 * 2);  // 2 MB
  float* bqkv  = (float*)alloc(3072 * 4);
  float* pmax  = (float*)alloc((size_t)8 * 8 * 2048 * 4);  // 512 KB
  u16*   QKV   = (u16*)alloc(ROWS * 3072 * 2);          // ~100.7 MB
  u16*   Wt    = (u16*)alloc(ROWS * 1024 * 2);          // 32 MB [8][1024][2048]

  // scores: NBCH batches of [2048 x 2048] bf16 per pass (8 MB each)
  const size_t CHUNK1 = (size_t)2048 * 2048 * 2;
  size_t avail = (ws_size > off) ? ws_size - off : 0;
  int NBCH = (int)(avail / CHUNK1);
  if (NBCH > 8) NBCH = 8;
  if (NBCH < 1) NBCH = 1;
  u16* sc = (u16*)(ws + off);

  ln_kernel<<<dim3(16384), dim3(256), 0, stream>>>(x, lnw, lnb, xn);
  dim3 tb(32, 8);
  transpose_w<<<dim3(32, 32), tb, 0, stream>>>(wq, wqkvt, 1024, 1024);
  transpose_w<<<dim3(32, 32), tb, 0, stream>>>(wk, wqkvt + (size_t)1024 * 1024, 1024, 1024);
  transpose_w<<<dim3(32, 32), tb, 0, stream>>>(wv, wqkvt + (size_t)2048 * 1024, 1024, 1024);
  transpose_w<<<dim3(32, 32), tb, 0, stream>>>(w0, w0t, 1024, 1024);
  concat_bias<<<dim3(3), dim3(1024), 0, stream>>>(bq, bk, bv, bqkv);

  // Fused QKV projection: [16384,1024] @ [1024,3072] -> QKV (BM=256 path)
  gemm_qkv<<<dim3(12, 64, 1), dim3(512), 0, stream>>>(xn, wqkvt, QKV, bqkv);

  float qk_scale = (float)(1.0 / (std::sqrt(1024.0) + 1e-9));

  for (int bA = 0; bA < 8; bA += NBCH) {
    int nb = 8 - bA;
    if (nb > NBCH) nb = NBCH;
    int wtB = (bA == 0) ? 512 : 0;  // Wt for ALL batches rides the first pass
    gemm_qkwt<<<dim3(wtB + nb * 72), dim3(512), 0, stream>>>(
        QKV, w0t, Wt, sc, pmax, wtB, bA, qk_scale);
    softmax_kernel<<<dim3(nb * 2048), dim3(256), 0, stream>>>(sc, pmax, bA);
    gemm_pv<<<dim3(64 * nb), dim3(512), 0, stream>>>(
        sc, Wt, out, b0, nb, bA);
  }
}

// Round 7
// 351.387 us; speedup vs baseline: 1.3528x; 1.0810x over previous
//
#include <hip/hip_runtime.h>
#include <cmath>

using u16 = unsigned short;
using u32 = unsigned int;
using bf16x8 = __attribute__((ext_vector_type(8))) __bf16;
using f32x4  = __attribute__((ext_vector_type(4))) float;

__device__ inline u16 f2bf(float f) {
  u32 u = __float_as_uint(f);
  u32 r = (u + 0x7fffu + ((u >> 16) & 1u)) >> 16;  // RNE
  return (u16)r;
}

// ---------------- LayerNorm: x[row][1024] f32 -> xn bf16 ----------------
__global__ __launch_bounds__(256) void ln_kernel(
    const float* __restrict__ x, const float* __restrict__ w,
    const float* __restrict__ b, u16* __restrict__ xn) {
  int row = blockIdx.x;
  const float4* xr = (const float4*)(x + (size_t)row * 1024);
  float4 v = xr[threadIdx.x];
  float s  = v.x + v.y + v.z + v.w;
  float ss = v.x * v.x + v.y * v.y + v.z * v.z + v.w * v.w;
  int lane = threadIdx.x & 63, wave = threadIdx.x >> 6;
#pragma unroll
  for (int o = 32; o >= 1; o >>= 1) {
    s  += __shfl_xor(s, o, 64);
    ss += __shfl_xor(ss, o, 64);
  }
  __shared__ float rs[4], rq[4];
  if (lane == 0) { rs[wave] = s; rq[wave] = ss; }
  __syncthreads();
  s  = rs[0] + rs[1] + rs[2] + rs[3];
  ss = rq[0] + rq[1] + rq[2] + rq[3];
  float mean = s * (1.0f / 1024.0f);
  float var  = ss * (1.0f / 1024.0f) - mean * mean;
  float rstd = rsqrtf(var + 1e-5f);
  int c = threadIdx.x * 4;
  ushort4 ov;
  ov.x = f2bf((v.x - mean) * rstd * w[c + 0] + b[c + 0]);
  ov.y = f2bf((v.y - mean) * rstd * w[c + 1] + b[c + 1]);
  ov.z = f2bf((v.z - mean) * rstd * w[c + 2] + b[c + 2]);
  ov.w = f2bf((v.w - mean) * rstd * w[c + 3] + b[c + 3]);
  ((ushort4*)(xn + (size_t)row * 1024))[threadIdx.x] = ov;
}

// ---------------- weight transpose f32 [R][C] -> bf16 [C][R] ----------------
__global__ __launch_bounds__(256) void transpose_w(
    const float* __restrict__ in, u16* __restrict__ out, int R, int C) {
  __shared__ float tile[32][33];
  int c0 = blockIdx.x * 32, r0 = blockIdx.y * 32;
  int tx = threadIdx.x, ty = threadIdx.y;  // block (32,8)
#pragma unroll
  for (int i = 0; i < 32; i += 8)
    tile[ty + i][tx] = in[(size_t)(r0 + ty + i) * C + c0 + tx];
  __syncthreads();
#pragma unroll
  for (int i = 0; i < 32; i += 8)
    out[(size_t)(c0 + ty + i) * R + r0 + tx] = f2bf(tile[tx][ty + i]);
}

// ---------------- bias concat: bq|bk|bv -> bqkv[3072] ----------------
__global__ void concat_bias(const float* __restrict__ bq, const float* __restrict__ bk,
                            const float* __restrict__ bv, float* __restrict__ o) {
  int i = blockIdx.x * 1024 + threadIdx.x;
  const float* src = (blockIdx.x == 0) ? bq : (blockIdx.x == 1) ? bk : bv;
  o[i] = src[threadIdx.x];
}

// --------- rowinv: inv[bz][s] = 1 / sum_{tj >= s>>8} sumP[bz][tj][s] ---------
__global__ void rowinv_kernel(const float* __restrict__ sumP,
                              float* __restrict__ inv, int bA) {
  int r = blockIdx.x * 256 + threadIdx.x;
  int bz = bA + (r >> 11), s = r & 2047;
  float t = 0.f;
  for (int tj = s >> 8; tj < 8; ++tj)
    t += sumP[((size_t)bz * 8 + tj) * 2048 + s];
  inv[(size_t)bz * 2048 + s] = 1.0f / t;
}

// ---------------- BMx256 8-phase bf16 GEMM body, B^T layout ----------------
// C[M,N] = A[M,K] * Bt[N,K]^T. BK=64, 8 waves (2Mx4N), wave tile (BM/2)x64.
// R3-verified schedule: half-tiles in READ-ORDER, 1 half staged per phase,
// counted vmcnt at P4/P8 (BM=256: 6 in flight; BM=128: 5), VM0 tail.
// T2 st-swizzle both-sides, T5 setprio, explicit LGKM0 before MFMA.
// EPI 0: bf16 out (+bias, scale). EPI 1: QK — E=exp(clamp(v)-5), diag mask,
// bf16 store + per-row partial sums -> sumP (softmax max pass eliminated;
// shift-invariance). EPI 2: PV — f32 out = acc*inv[row] + bias.
template <int BM, int EPI>
__device__ __forceinline__ void gemm_body(
    const u16* __restrict__ Ab, const u16* __restrict__ Bb,
    void* __restrict__ Cp, const float* __restrict__ bias,
    int K, int k0, int lda, int ldb, int ldc, float scale, size_t cbase,
    int ti, int tj, u16* __restrict__ AsP, u16* __restrict__ BsP,
    float* __restrict__ sumP, int diag, const float* __restrict__ invRow) {
  constexpr int WM = BM / 2;    // wave tile M
  constexpr int MH = BM / 64;   // m-frags per qm half
  constexpr int FM = 2 * MH;    // m-frags per wave
  constexpr int HR = BM / 4;    // rows per A read-order half
  constexpr int LA = BM / 128;  // GLLs per thread per A half

  const int tid = threadIdx.x;
  const int wave = tid >> 6, lane = tid & 63;
  const int wr = wave >> 2, wc = wave & 3;  // 2 x 4 wave grid
  const int fr = lane & 15;
  const int kb16 = (lane >> 4) * 16;        // byte offset of k-frag in 64B k-block
  const int swz = (fr & 7) << 4;
  const int cs0 = kb16 ^ swz;               // ks=0 swizzled col byte
  const int cs1 = (64 + kb16) ^ swz;        // ks=1
  const int aRowOff = (wr * WM + fr) * 128;  // bytes
  const int bRowOff = (wc * 64 + fr) * 128;

  // Staging precompute
  size_t gAo[2][LA], gBo[2][2];
  u32 ldsA[2][LA], ldsB[2][2];
#pragma unroll
  for (int h = 0; h < 2; ++h) {
#pragma unroll
    for (int l = 0; l < LA; ++l) {
      int i = l * 512 + tid;
      int rih = i >> 3, ch8 = i & 7;
      int rA = (rih % HR) + (rih / HR) * WM + h * HR;
      int cbA = (ch8 << 4) ^ ((rA & 7) << 4);  // pre-swizzled source byte col
      gAo[h][l] = (size_t)rA * lda + (cbA >> 1);
      ldsA[h][l] = (u32)(rA * 8 + ch8) * 16;
    }
#pragma unroll
    for (int l = 0; l < 2; ++l) {
      int i = l * 512 + tid;
      int rih = i >> 3, ch8 = i & 7;
      int rB = (rih & 31) + ((rih >> 5) << 6) + h * 32;
      int cbB = (ch8 << 4) ^ ((rB & 7) << 4);
      gBo[h][l] = (size_t)rB * ldb + (cbB >> 1);
      ldsB[h][l] = (u32)(rB * 8 + ch8) * 16;
    }
  }
  const size_t aBase = (size_t)(ti * BM) * lda;
  const size_t bBase = (size_t)(tj * 256) * ldb;
  const int niter = (K - k0) / 128;  // 2 K-tiles per iteration

  f32x4 acc[FM][4] = {};
  bf16x8 aF[MH][2], bF[4][2];

#define GLL(gaddr, laddr)                                        \
  __builtin_amdgcn_global_load_lds(                              \
      (const __attribute__((address_space(1))) void*)(gaddr),    \
      (__attribute__((address_space(3))) void*)(laddr), 16, 0, 0)

#define STAGE_A(buf, h, t)                                                   \
  do {                                                                       \
    const size_t _kt = aBase + (size_t)(k0 + (t) * 64);                      \
    _Pragma("unroll") for (int _l = 0; _l < LA; ++_l)                        \
        GLL(Ab + _kt + gAo[h][_l],                                           \
            (char*)(AsP + (buf) * (BM * 64)) + ldsA[h][_l]);                 \
  } while (0)
#define STAGE_B(buf, h, t)                                                   \
  do {                                                                       \
    const size_t _kt = bBase + (size_t)(k0 + (t) * 64);                      \
    _Pragma("unroll") for (int _l = 0; _l < 2; ++_l)                         \
        GLL(Bb + _kt + gBo[h][_l],                                           \
            (char*)(BsP + (buf) * (256 * 64)) + ldsB[h][_l]);                \
  } while (0)

#define DS_A(buf, qm)                                                        \
  do {                                                                       \
    const char* _pa =                                                        \
        (const char*)(AsP + (buf) * (BM * 64)) + aRowOff + (qm) * (MH * 2048); \
    _Pragma("unroll") for (int mm = 0; mm < MH; ++mm) {                      \
      aF[mm][0] = *(const bf16x8*)(_pa + mm * 2048 + cs0);                   \
      aF[mm][1] = *(const bf16x8*)(_pa + mm * 2048 + cs1);                   \
    }                                                                        \
  } while (0)
#define DS_B(buf, nh)                                                        \
  do {                                                                       \
    const char* _pb = (const char*)(BsP + (buf) * (256 * 64)) + bRowOff;     \
    _Pragma("unroll") for (int nn = 0; nn < 2; ++nn) {                       \
      bF[(nh)*2 + nn][0] = *(const bf16x8*)(_pb + ((nh)*2 + nn) * 2048 + cs0); \
      bF[(nh)*2 + nn][1] = *(const bf16x8*)(_pb + ((nh)*2 + nn) * 2048 + cs1); \
    }                                                                        \
  } while (0)

#define MMA(qm, nh)                                                          \
  do {                                                                       \
    _Pragma("unroll") for (int mm = 0; mm < MH; ++mm)                        \
    _Pragma("unroll") for (int nn = 0; nn < 2; ++nn) {                       \
      f32x4 _c = acc[(qm)*MH + mm][(nh)*2 + nn];                             \
      _c = __builtin_amdgcn_mfma_f32_16x16x32_bf16(aF[mm][0], bF[(nh)*2+nn][0], _c, 0, 0, 0); \
      _c = __builtin_amdgcn_mfma_f32_16x16x32_bf16(aF[mm][1], bF[(nh)*2+nn][1], _c, 0, 0, 0); \
      acc[(qm)*MH + mm][(nh)*2 + nn] = _c;                                   \
    }                                                                        \
  } while (0)

#define BAR __builtin_amdgcn_s_barrier()
#define LGKM0 asm volatile("s_waitcnt lgkmcnt(0)" ::: "memory")
#define VMN                                                                  \
  do {                                                                       \
    if constexpr (BM == 256)                                                 \
      asm volatile("s_waitcnt vmcnt(6)" ::: "memory");                       \
    else                                                                     \
      asm volatile("s_waitcnt vmcnt(5)" ::: "memory");                       \
  } while (0)
#define VM0 asm volatile("s_waitcnt vmcnt(0)" ::: "memory")
#define PRIO1 __builtin_amdgcn_s_setprio(1)
#define PRIO0 __builtin_amdgcn_s_setprio(0)

  // Prologue: tile0 all 4 halves (read-order) + tile1 B-h0,B-h1,A-h0.
  STAGE_B(0, 0, 0); STAGE_B(0, 1, 0); STAGE_A(0, 0, 0); STAGE_A(0, 1, 0);
  STAGE_B(1, 0, 1); STAGE_B(1, 1, 1); STAGE_A(1, 0, 1);
  VMN; BAR;  // tile0 fully landed; 3 half-tiles (tile1 B+A-h0) in flight

  for (int it = 0; it < niter; ++it) {
    const bool last = (it == niter - 1);
    const int t1g = 2 * it + 1, t2g = 2 * it + 2, t3g = 2 * it + 3;

    // ---- P1: read buf0 qm0+nh0; stage A-h1(t1g)->buf1
    DS_A(0, 0); DS_B(0, 0);
    STAGE_A(1, 1, t1g);
    BAR; LGKM0; PRIO1; MMA(0, 0); PRIO0; BAR;
    // ---- P2: read buf0 nh1; stage B-h0(t2g)->buf0
    DS_B(0, 1);
    if (!last) STAGE_B(0, 0, t2g);
    BAR; LGKM0; PRIO1; MMA(0, 1); PRIO0; BAR;
    // ---- P3: read buf0 qm1; stage B-h1(t2g)
    DS_A(0, 1);
    if (!last) STAGE_B(0, 1, t2g);
    BAR; LGKM0; PRIO1; MMA(1, 0); PRIO0; BAR;
    // ---- P4: stage A-h0(t2g); K-tile wait (lands ALL of tile t1g)
    if (!last) STAGE_A(0, 0, t2g);
    BAR; PRIO1; MMA(1, 1); PRIO0;
    if (last) { VM0; } else { VMN; }
    BAR;
    // ---- P5: read buf1 qm0+nh0; stage A-h1(t2g)
    DS_A(1, 0); DS_B(1, 0);
    if (!last) STAGE_A(0, 1, t2g);
    BAR; LGKM0; PRIO1; MMA(0, 0); PRIO0; BAR;
    // ---- P6: read buf1 nh1; stage B-h0(t3g)->buf1
    DS_B(1, 1);
    if (!last) STAGE_B(1, 0, t3g);
    BAR; LGKM0; PRIO1; MMA(0, 1); PRIO0; BAR;
    // ---- P7: read buf1 qm1; stage B-h1(t3g)
    DS_A(1, 1);
    if (!last) STAGE_B(1, 1, t3g);
    BAR; LGKM0; PRIO1; MMA(1, 0); PRIO0; BAR;
    // ---- P8: stage A-h0(t3g); K-tile wait (lands ALL of tile t2g)
    if (!last) STAGE_A(1, 0, t3g);
    BAR; PRIO1; MMA(1, 1); PRIO0;
    if (!last) VMN;
    BAR;
  }

  // Epilogue: C/D layout col=lane&15, row=(lane>>4)*4+j
  const int orow0 = ti * BM + wr * WM + ((lane >> 4) << 2);
  const int ocol0 = tj * 256 + wc * 64 + fr;

  if constexpr (EPI == 1) {
    // QK: E = exp(clamp(v)-5); diagonal mask; bf16 store; row partial sums.
    float* slds = (float*)AsP;  // [256][4] cross-wave reduce buffer
    const int rl0 = wr * WM + ((lane >> 4) << 2);
#pragma unroll
    for (int m = 0; m < FM; ++m) {
#pragma unroll
      for (int j = 0; j < 4; ++j) {
        const int rl = rl0 + m * 16 + j;
        const int row = ti * BM + rl;
        float rsum = 0.f;
#pragma unroll
        for (int n = 0; n < 4; ++n) {
          const int cl = wc * 64 + fr + n * 16;
          float v = acc[m][n][j] * scale;
          v = fminf(fmaxf(v, -1.0e9f), 1.0e9f);  // CLAMP
          v = fminf(v, 60.0f);                   // overflow guard
          float e = __expf(v - 5.0f);
          if (diag && cl < rl) e = 0.f;
          rsum += e;
          ((u16*)Cp)[cbase + (size_t)row * ldc + ocol0 + n * 16] = f2bf(e);
        }
        rsum += __shfl_xor(rsum, 1, 64);
        rsum += __shfl_xor(rsum, 2, 64);
        rsum += __shfl_xor(rsum, 4, 64);
        rsum += __shfl_xor(rsum, 8, 64);
        if (fr == 0) slds[rl * 4 + wc] = rsum;
      }
    }
    __syncthreads();
    if (tid < 256) {
      float t = slds[tid * 4 + 0] + slds[tid * 4 + 1] +
                slds[tid * 4 + 2] + slds[tid * 4 + 3];
      sumP[ti * BM + tid] = t;
    }
  } else {
#pragma unroll
    for (int m = 0; m < FM; ++m) {
#pragma unroll
      for (int j = 0; j < 4; ++j) {
        const int row = orow0 + m * 16 + j;
        float mul = (EPI == 2) ? invRow[row] : scale;
#pragma unroll
        for (int n = 0; n < 4; ++n) {
          const int col = ocol0 + n * 16;
          const float bv = bias ? bias[col] : 0.0f;
          const float v = acc[m][n][j] * mul + bv;
          const size_t idx = cbase + (size_t)row * ldc + col;
          if (EPI == 2) ((float*)Cp)[idx] = v;
          else          ((u16*)Cp)[idx]   = f2bf(v);
        }
      }
    }
  }
#undef GLL
#undef STAGE_A
#undef STAGE_B
#undef DS_A
#undef DS_B
#undef MMA
#undef BAR
#undef LGKM0
#undef VMN
#undef VM0
#undef PRIO1
#undef PRIO0
}

// ---------------- QKV projection wrapper (BM=256), XCD-swizzled grid --------
__global__ __launch_bounds__(512, 2) void gemm_qkv(
    const u16* __restrict__ A, const u16* __restrict__ B, u16* __restrict__ Cv,
    const float* __restrict__ bias) {
  __shared__ u16 As[2][256 * 64];
  __shared__ u16 Bs[2][256 * 64];
  int gx = gridDim.x;
  int wg = blockIdx.y * gx + blockIdx.x;
  int nwg = gx * gridDim.y;
  if ((nwg & 7) == 0) { int q = nwg >> 3; wg = (wg & 7) * q + (wg >> 3); }
  const int ti = wg / gx, tj = wg % gx;
  gemm_body<256, 0>(A, B, Cv, bias, 1024, 0, 1024, 1024, 3072, 1.0f, 0,
                    ti, tj, &As[0][0], &Bs[0][0], nullptr, 0, nullptr);
}

// ---------------- combined Wt + QK^T dispatch (both BM=256) -----------------
// x < wtBlocks: Wt[bz][e][t] = sum_d w0t[e,d] V[bz][t,d]; 4 ti-sharers of a
// V-slice get the same blockIdx%8 (XCD co-location heuristic).
// else: QK tile (tq,tj), tj>=tq triangular; EPI=1 (exp + sumP).
__global__ __launch_bounds__(512, 2) void gemm_qkwt(
    const u16* __restrict__ QKVp, const u16* __restrict__ w0t,
    u16* __restrict__ Wt, u16* __restrict__ sc, float* __restrict__ sumP,
    int wtBlocks, int b0, float qk_scale) {
  __shared__ u16 As[2][256 * 64];
  __shared__ u16 Bs[2][256 * 64];
  const long long sQKV = 2048LL * 3072, sWt = 1024LL * 2048, sS = 2048LL * 2048;
  int x = blockIdx.x;
  if (x < wtBlocks) {
    int r = x & 7, o = x >> 3;
    int ti = o & 3, bztj = r + 8 * (o >> 2);
    int bz = bztj >> 3, tj = bztj & 7;
    gemm_body<256, 0>(w0t, QKVp + (size_t)bz * sQKV + 2048, Wt, nullptr,
                      1024, 0, 1024, 3072, 2048, 1.0f, (size_t)bz * sWt,
                      ti, tj, &As[0][0], &Bs[0][0], nullptr, 0, nullptr);
  } else {
    int q = x - wtBlocks;
    int bz = b0 + q / 36, t36 = q % 36;
    int tj = 0, accm = 0;
    while (t36 >= accm + tj + 1) { accm += tj + 1; ++tj; }
    int tq = t36 - accm;
    const u16* Ab = QKVp + (size_t)bz * sQKV;
    gemm_body<256, 1>(Ab, Ab + 1024, sc, nullptr, 1024, 0, 3072, 3072, 2048,
                      qk_scale, (size_t)(bz - b0) * sS, tq, tj,
                      &As[0][0], &Bs[0][0],
                      sumP + ((size_t)bz * 8 + tj) * 2048, tq == tj, nullptr);
  }
}

// ---------------- PV dispatch (BM=128), LPT ti-major; EPI=2 normalize -------
__global__ __launch_bounds__(512, 2) void gemm_pv(
    const u16* __restrict__ sc, const u16* __restrict__ Wt,
    float* __restrict__ out, const float* __restrict__ b0v,
    const float* __restrict__ inv, int nb, int bA) {
  __shared__ u16 As[2][128 * 64];
  __shared__ u16 Bs[2][256 * 64];
  const long long sP = 2048LL * 2048, sWt = 1024LL * 2048, sH = 2048LL * 1024;
  int x = blockIdx.x;
  int g = 4 * nb;
  int ti = x / g, r = x % g;
  int bzl = r >> 2, tj = r & 3;
  int bz = bA + bzl;
  gemm_body<128, 2>(sc + (size_t)bzl * sP, Wt + (size_t)bz * sWt, out, b0v,
                    2048, ti * 128, 2048, 2048, 1024, 1.0f, (size_t)bz * sH,
                    ti, tj, &As[0][0], &Bs[0][0], nullptr, 0,
                    inv + (size_t)bz * 2048);
}

extern "C" void kernel_launch(void* const* d_in, const int* in_sizes, int n_in,
                              void* d_out, int out_size, void* d_ws, size_t ws_size,
                              hipStream_t stream) {
  (void)in_sizes; (void)n_in; (void)out_size;
  const float* x   = (const float*)d_in[0];
  const float* lnw = (const float*)d_in[1];
  const float* lnb = (const float*)d_in[2];
  const float* wq  = (const float*)d_in[3];
  const float* bq  = (const float*)d_in[4];
  const float* wk  = (const float*)d_in[5];
  const float* bk  = (const float*)d_in[6];
  const float* wv  = (const float*)d_in[7];
  const float* bv  = (const float*)d_in[8];
  const float* w0  = (const float*)d_in[9];
  const float* b0  = (const float*)d_in[10];
  float* out = (float*)d_out;

  const size_t ROWS = 16384;  // B*S
  char* ws = (char*)d_ws;
  size_t off = 0;
  auto alloc = [&](size_t bytes) -> void* {
    void* p = ws + off;
    off += (bytes + 255) & ~(size_t)255;
    return p;
  };
  u16*   xn    = (u16*)alloc(ROWS * 1024 * 2);          // 32 MB
  u16*   wqkvt = (u16*)alloc((size_t)3072 * 1024 * 2);  // 6 MB
  u16*   w0t   = (u16*)alloc((size_t)1024 * 1024 * 2);  // 2 MB
  float* bqkv  = (float*)alloc(3072 * 4);
  float* sumP  = (float*)alloc((size_t)8 * 8 * 2048 * 4);  // 512 KB
  float* inv   = (float*)alloc((size_t)8 * 2048 * 4);      // 64 KB
  u16*   QKV   = (u16*)alloc(ROWS * 3072 * 2);          // ~100.7 MB
  u16*   Wt    = (u16*)alloc(ROWS * 1024 * 2);          // 32 MB [8][1024][2048]

  // scores (E bf16): NBCH batches of [2048 x 2048] per pass (8 MB each)
  const size_t CHUNK1 = (size_t)2048 * 2048 * 2;
  size_t avail = (ws_size > off) ? ws_size - off : 0;
  int NBCH = (int)(avail / CHUNK1);
  if (NBCH > 8) NBCH = 8;
  if (NBCH < 1) NBCH = 1;
  u16* sc = (u16*)(ws + off);

  ln_kernel<<<dim3(16384), dim3(256), 0, stream>>>(x, lnw, lnb, xn);
  dim3 tb(32, 8);
  transpose_w<<<dim3(32, 32), tb, 0, stream>>>(wq, wqkvt, 1024, 1024);
  transpose_w<<<dim3(32, 32), tb, 0, stream>>>(wk, wqkvt + (size_t)1024 * 1024, 1024, 1024);
  transpose_w<<<dim3(32, 32), tb, 0, stream>>>(wv, wqkvt + (size_t)2048 * 1024, 1024, 1024);
  transpose_w<<<dim3(32, 32), tb, 0, stream>>>(w0, w0t, 1024, 1024);
  concat_bias<<<dim3(3), dim3(1024), 0, stream>>>(bq, bk, bv, bqkv);

  // Fused QKV projection: [16384,1024] @ [1024,3072] -> QKV
  gemm_qkv<<<dim3(12, 64, 1), dim3(512), 0, stream>>>(xn, wqkvt, QKV, bqkv);

  float qk_scale = (float)(1.0 / (std::sqrt(1024.0) + 1e-9));

  for (int bA = 0; bA < 8; bA += NBCH) {
    int nb = 8 - bA;
    if (nb > NBCH) nb = NBCH;
    int wtB = (bA == 0) ? 256 : 0;  // Wt for ALL batches rides the first pass
    gemm_qkwt<<<dim3(wtB + nb * 36), dim3(512), 0, stream>>>(
        QKV, w0t, Wt, sc, sumP, wtB, bA, qk_scale);
    rowinv_kernel<<<dim3(nb * 8), dim3(256), 0, stream>>>(sumP, inv, bA);
    gemm_pv<<<dim3(64 * nb), dim3(512), 0, stream>>>(
        sc, Wt, out, b0, inv, nb, bA);
  }
}